// Round 7
// baseline (350.195 us; speedup 1.0000x reference)
//
#include <hip/hip_runtime.h>
#include <math.h>

#define N_ATOMS   20000
#define N_NBR     32
#define NBR_TOTAL (N_ATOMS * N_NBR)     // 640000
#define N_TILES   (NBR_TOTAL / 64)      // 10000 wave-tiles (64 neighbors each)
#define N_ELEM    83
#define NUM_EMB   64
#define ROWF      36                    // floats per LDS row: 144 B, 16B-aligned
#define NBLK      1024                  // 4 blocks/CU resident (LDS 36.9KB/block)
#define NTHR      256
#define WAVES_TOTAL (NBLK * NTHR / 64)  // 4096

typedef float f32x4 __attribute__((ext_vector_type(4)));

// ---- tiny pre-kernel: F[z][f] = embed[z]@dense_w[:,f] + db[f], once per launch ----
__global__ __launch_bounds__(256) void f_table_kernel(
    const float* __restrict__ embed, const float* __restrict__ dw,
    const float* __restrict__ db, float* __restrict__ F)
{
    const int i = blockIdx.x * 256 + threadIdx.x;
    if (i < N_ELEM * 8) {
        const int z = i >> 3, f = i & 7;
        float acc = db[f];
        const float* er = embed + z * NUM_EMB;
        #pragma unroll 8
        for (int e = 0; e < NUM_EMB; ++e)
            acc = fmaf(er[e], dw[e * 8 + f], acc);
        F[i] = acc;
    }
}

// Persistent wave-autonomous kernel: each wave loops over 64-neighbor tiles.
// Per tile: compute 32 scalars/neighbor -> wave-private LDS -> 32 coalesced
// 1KB f32x4 wave-stores. NO __syncthreads (no vmcnt(0) drain in the loop):
// intra-wave lgkmcnt(0) is the only sync; stores stay in flight across tiles.
__global__ __launch_bounds__(256) void sarb_kernel(
    const float* __restrict__ disp,   // (N, K, 3)
    const int*   __restrict__ Zj,     // (N, K)
    const float* __restrict__ tw,     // (4, 8)
    const float* __restrict__ Fg,     // (83, 8) precomputed
    float* __restrict__ out)          // (N, K, 1, 16, 8) fp32
{
    __shared__ __align__(16) float lds[4 * 64 * ROWF];   // 36,864 B

    const int tid  = threadIdx.x;
    const int lane = tid & 63;
    const int wib  = tid >> 6;                       // wave within block
    const int gw   = blockIdx.x * 4 + wib;           // global wave id
    float* __restrict__ wlds = lds + wib * 64 * ROWF;

    // ---- per-lane store-phase constants (loop-invariant) ----
    const int c   = lane & 31;       // f32x4 chunk within a neighbor's 128 floats
    const int lm  = c >> 1;
    const int fh4 = c & 1;
    const int hi  = lane >> 5;       // 0: even neighbor of pair, 1: odd
    const int l   = (lm > 0) + (lm > 3) + (lm > 8);
    f32x4 wv;
    if (lm == 0) { wv = (f32x4){1.0f, 1.0f, 1.0f, 1.0f}; }
    else         { wv = *reinterpret_cast<const f32x4*>(tw + l * 8 + fh4 * 4); }
    const int goff = (lm ? 16 : 24) + fh4 * 4;       // g for lm>0, h for lm==0
    const float* __restrict__ rd_s = wlds + hi * ROWF + lm;
    const float* __restrict__ rd_g = wlds + hi * ROWF + goff;

    // hoisted small tables
    float twv[8], Fv[8];
    #pragma unroll
    for (int i = 0; i < 8; ++i) twv[i] = tw[i];      // tensor_w row l=0 (for h)

    // even range partition of tiles over waves (each wave: 2-3 consecutive tiles)
    const int t0 = (int)(((long long)gw       * N_TILES) / WAVES_TOTAL);
    const int t1 = (int)(((long long)(gw + 1) * N_TILES) / WAVES_TOTAL);

    for (int t = t0; t < t1; ++t) {
        const int n = (t << 6) + lane;
        const float dx = disp[3 * n + 0];
        const float dy = disp[3 * n + 1];
        const float dz = disp[3 * n + 2];
        const int   z  = Zj[n];

        const float nrm = sqrtf(dx * dx + dy * dy + dz * dz);
        const float inv = 1.0f / nrm;                // nrm > 0 a.s.
        const float x = dx * inv, y = dy * inv, zu = dz * inv;

        const float s3 = 1.7320508075688772f, s6 = 2.449489742783178f;
        const float s10 = 3.1622776601683795f, s15 = 3.872983346207417f;
        const float x2 = x * x, y2 = y * y, z2 = zu * zu;
        const float xy = x * y, yz = y * zu, xz = x * zu;

        const f32x4 sA = {1.0f, y, zu, x};
        const f32x4 sB = {s3 * xy, s3 * yz, 0.5f * (3.0f * z2 - 1.0f), s3 * xz};
        const f32x4 sC = {0.5f * s3 * (x2 - y2), 0.25f * s10 * y * (3.0f * x2 - y2),
                          s15 * xy * zu, 0.25f * s6 * y * (5.0f * z2 - 1.0f)};
        const f32x4 sD = {0.5f * zu * (5.0f * z2 - 3.0f), 0.25f * s6 * x * (5.0f * z2 - 1.0f),
                          0.5f * s15 * zu * (x2 - y2), 0.25f * s10 * x * (x2 - 3.0f * y2)};

        // radial: sinc(k*a)/(k*a), k=1..9, Chebyshev recurrence; a = pi*r/5
        const float a = 0.6283185307179586f * nrm;
        float sv[9];
        {
            float s1, c1;
            __sincosf(a, &s1, &c1);
            const float c2   = 2.0f * c1;
            const float inva = 1.0f / a;
            const float invk[9] = {1.0f, 0.5f, 0.33333334f, 0.25f, 0.2f,
                                   0.16666667f, 0.14285715f, 0.125f, 0.11111111f};
            float sprev = 0.0f, scur = s1;
            #pragma unroll
            for (int k = 0; k < 9; ++k) {
                sv[k] = scur * inva * invk[k];
                const float snext = c2 * scur - sprev;
                sprev = scur; scur = snext;
            }
            if (a < 1e-12f) {
                #pragma unroll
                for (int k = 0; k < 9; ++k) sv[k] = 1.0f;
            }
        }

        *reinterpret_cast<f32x4*>(Fv)     = *reinterpret_cast<const f32x4*>(Fg + z * 8);
        *reinterpret_cast<f32x4*>(Fv + 4) = *reinterpret_cast<const f32x4*>(Fg + z * 8 + 4);

        float gv[8], hv[8];
        #pragma unroll
        for (int i = 0; i < 8; ++i) {
            const float ip1 = (float)(i + 1), ip2 = (float)(i + 2);
            float f2 = ip1 * ip2 / sqrtf(ip1 * ip1 + ip2 * ip2);
            if (i & 1) f2 = -f2;
            const float rbf = 0.3973835397f * f2 * (sv[i] + sv[i + 1]);
            const float tf  = Fv[i];
            gv[i] = tf * rbf;                        // t*rbf  (lm>0)
            hv[i] = fmaf(twv[i] * rbf, tf, tf);      // full l=0 row incl. residual
        }

        // wave-private LDS row (lane-owned): 8 aligned b128 writes
        float* __restrict__ rowp = wlds + lane * ROWF;
        *reinterpret_cast<f32x4*>(rowp +  0) = sA;
        *reinterpret_cast<f32x4*>(rowp +  4) = sB;
        *reinterpret_cast<f32x4*>(rowp +  8) = sC;
        *reinterpret_cast<f32x4*>(rowp + 12) = sD;
        *reinterpret_cast<f32x4*>(rowp + 16) = (f32x4){gv[0], gv[1], gv[2], gv[3]};
        *reinterpret_cast<f32x4*>(rowp + 20) = (f32x4){gv[4], gv[5], gv[6], gv[7]};
        *reinterpret_cast<f32x4*>(rowp + 24) = (f32x4){hv[0], hv[1], hv[2], hv[3]};
        *reinterpret_cast<f32x4*>(rowp + 28) = (f32x4){hv[4], hv[5], hv[6], hv[7]};

        asm volatile("s_waitcnt lgkmcnt(0)" ::: "memory");  // intra-wave: writes visible
        __builtin_amdgcn_sched_barrier(0);

        // ---- store phase: 32 x 1KB coalesced wave-stores, stores never drained ----
        f32x4* __restrict__ outv = reinterpret_cast<f32x4*>(out) + (size_t)t * 2048 + lane;
        #pragma unroll
        for (int k = 0; k < 32; ++k) {
            const float s = rd_s[k * 2 * ROWF];                                  // ds b32
            const f32x4 g = *reinterpret_cast<const f32x4*>(rd_g + k * 2 * ROWF); // ds b128
            f32x4 r;
            r.x = wv.x * s * g.x;
            r.y = wv.y * s * g.y;
            r.z = wv.z * s * g.z;
            r.w = wv.w * s * g.w;
            outv[k * 64] = r;
        }

        asm volatile("s_waitcnt lgkmcnt(0)" ::: "memory");  // reads done before overwrite
        __builtin_amdgcn_sched_barrier(0);
    }
}

extern "C" void kernel_launch(void* const* d_in, const int* in_sizes, int n_in,
                              void* d_out, int out_size, void* d_ws, size_t ws_size,
                              hipStream_t stream) {
    const float* disp  = (const float*)d_in[0];
    const int*   Zj    = (const int*)  d_in[1];
    const float* embed = (const float*)d_in[2];
    const float* dw    = (const float*)d_in[3];
    const float* db    = (const float*)d_in[4];
    const float* tw    = (const float*)d_in[5];
    float* out = (float*)d_out;
    float* F   = (float*)d_ws;   // 664 floats of scratch

    f_table_kernel<<<dim3(3), dim3(256), 0, stream>>>(embed, dw, db, F);
    sarb_kernel<<<dim3(NBLK), dim3(NTHR), 0, stream>>>(disp, Zj, tw, F, out);
}